// Round 8
// baseline (296.532 us; speedup 1.0000x reference)
//
#include <hip/hip_runtime.h>

#define BB 64
#define SS 2048
#define DD 128
#define DDV 256
#define NCH 32          // S / 64 chunks for PV
#define RPC 64          // rows per chunk

// tanh(x) = 1 - 2/(e^{2x}+1) with raw v_rcp_f32 (no IEEE refine).
// |rel err| ~1e-7 vs 7.1e-3 output threshold (validated rounds 4-7).
__device__ __forceinline__ float fast_tanh(float x) {
    const float t = __expf(2.0f * x);
    return 1.0f - 2.0f * __builtin_amdgcn_rcpf(t + 1.0f);
}

// ---------------- Kernel 1: blend[b*S+s] = 0.5*scores1 ----------------
// (+0.5 shift dropped: cancels in softmax #1. 0.5 scale folded into w4.)
// 4 waves/block, 8 rows/wave -> 32 rows/block, 4096 blocks. Lanes 0-31 take
// the q half, 32-63 the k half; one float4 per lane per row. At the HBM
// floor (~20 us for 128 MiB). Block 0 also zeroes the per-batch counters
// used by k_pv's last-block reduction (fresh each call).
__global__ __launch_bounds__(256) void k_blend(const float* __restrict__ q,
                                               const float* __restrict__ k,
                                               const float* __restrict__ wv,
                                               float* __restrict__ blend,
                                               int* __restrict__ counters) {
    if (blockIdx.x == 0 && threadIdx.x < BB) counters[threadIdx.x] = 0;
    const int wave = threadIdx.x >> 6;
    const int lane = threadIdx.x & 63;
    const float* src = (lane < 32) ? q : k;
    float4 w4 = *(const float4*)(wv + lane * 4);
    w4.x *= 0.5f; w4.y *= 0.5f; w4.z *= 0.5f; w4.w *= 0.5f;
    const int row0 = blockIdx.x * 32 + wave * 8;
    const float* base = src + (size_t)row0 * DD + (lane & 31) * 4;
#pragma unroll
    for (int i = 0; i < 8; ++i) {
        const float4 x = *(const float4*)(base + (size_t)i * DD);
        float acc = fast_tanh(x.x) * w4.x + fast_tanh(x.y) * w4.y
                  + fast_tanh(x.z) * w4.z + fast_tanh(x.w) * w4.w;
#pragma unroll
        for (int o = 32; o; o >>= 1) acc += __shfl_xor(acc, o, 64);
        if (lane == 0) blend[row0 + i] = acc;
    }
}

// ---------------- Kernel 2: stats (inline) + PV partials + last-block reduce --
// grid (NCH, B), 256 threads. Every working block recomputes its batch's
// double-softmax stats from blend (L2-hot, 4 block reductions — redundant
// across the 32 chunks of a batch but fully parallel and bitwise identical).
// Then the proven PV pipeline; then partial write; the 32nd block to finish
// a batch reduces the 32 partials in fixed order -> out (deterministic).
__global__ __launch_bounds__(256) void k_pv(const float* __restrict__ blend,
                                            const int* __restrict__ valid,
                                            const float* __restrict__ values,
                                            float* __restrict__ partial,
                                            int* __restrict__ counters,
                                            float* __restrict__ out) {
    const int c = blockIdx.x, b = blockIdx.y;
    const int t = threadIdx.x;
    const int wid = t >> 6, lane = t & 63;
    const int s0 = c * RPC;
    __shared__ float red[4];
    __shared__ float wsm[RPC];
    __shared__ float4 sacc[256];
    __shared__ bool last;

    const int L = valid[b];
    float4 acc = {0.f, 0.f, 0.f, 0.f};

    if (s0 < L) {
        // ---- inline stats over the whole batch row ----
        const float* rowp = blend + (size_t)b * SS;
        float v[8];
#pragma unroll
        for (int i = 0; i < 8; ++i) v[i] = rowp[t + i * 256];

        float m = v[0];
#pragma unroll
        for (int i = 1; i < 8; ++i) m = fmaxf(m, v[i]);
#pragma unroll
        for (int o = 32; o; o >>= 1) m = fmaxf(m, __shfl_xor(m, o, 64));
        if (lane == 0) red[wid] = m;
        __syncthreads();
        const float m1 = fmaxf(fmaxf(red[0], red[1]), fmaxf(red[2], red[3]));
        __syncthreads();

        float e[8]; float s = 0.f;
#pragma unroll
        for (int i = 0; i < 8; ++i) { e[i] = expf(v[i] - m1); s += e[i]; }
#pragma unroll
        for (int o = 32; o; o >>= 1) s += __shfl_xor(s, o, 64);
        if (lane == 0) red[wid] = s;
        __syncthreads();
        const float Z1 = red[0] + red[1] + red[2] + red[3];
        __syncthreads();
        const float invZ1 = 1.f / Z1;

        float mm = -1e30f;
#pragma unroll
        for (int i = 0; i < 8; ++i)
            if (t + i * 256 < L) mm = fmaxf(mm, e[i] * invZ1);
#pragma unroll
        for (int o = 32; o; o >>= 1) mm = fmaxf(mm, __shfl_xor(mm, o, 64));
        if (lane == 0) red[wid] = mm;
        __syncthreads();
        const float m2 = fmaxf(fmaxf(red[0], red[1]), fmaxf(red[2], red[3]));
        __syncthreads();

        float s2 = 0.f;
#pragma unroll
        for (int i = 0; i < 8; ++i)
            if (t + i * 256 < L) s2 += expf(e[i] * invZ1 - m2);
#pragma unroll
        for (int o = 32; o; o >>= 1) s2 += __shfl_xor(s2, o, 64);
        if (lane == 0) red[wid] = s2;
        __syncthreads();
        const float Z2 = red[0] + red[1] + red[2] + red[3];
        const float invZ2 = 1.f / Z2;

        // ---- weights for this chunk's 64 rows ----
        if (t < RPC) {
            const int s_ = s0 + t;
            float w = 0.f;
            if (s_ < L)
                w = expf(expf(rowp[s_] - m1) * invZ1 - m2) * invZ2;
            wsm[t] = w;
        }
        __syncthreads();

        // ---- PV ----
        float wr[16];
        bool any = false;
#pragma unroll
        for (int i = 0; i < 16; ++i) { wr[i] = wsm[wid * 16 + i]; any |= (wr[i] != 0.f); }
        if (any) {
            const float* vb = values + ((size_t)b * SS + s0 + wid * 16) * DDV + lane * 4;
#pragma unroll
            for (int i = 0; i < 16; ++i) {
                const float4 v4 = *(const float4*)(vb + (size_t)i * DDV);
                acc.x += wr[i] * v4.x;
                acc.y += wr[i] * v4.y;
                acc.z += wr[i] * v4.z;
                acc.w += wr[i] * v4.w;
            }
        }
    }

    sacc[t] = acc;
    __syncthreads();
    if (t < 64) {
        const float4 a0 = sacc[t], a1 = sacc[t + 64], a2 = sacc[t + 128], a3 = sacc[t + 192];
        float4 r;
        r.x = a0.x + a1.x + a2.x + a3.x;
        r.y = a0.y + a1.y + a2.y + a3.y;
        r.z = a0.z + a1.z + a2.z + a3.z;
        r.w = a0.w + a1.w + a2.w + a3.w;
        *(float4*)(partial + ((size_t)(b * NCH + c)) * 256 + t * 4) = r;
    }

    // ---- last-block-per-batch reduction (deterministic fixed-order sum) ----
    __threadfence();                    // make partial visible device-wide
    __syncthreads();
    if (t == 0) last = (atomicAdd(&counters[b], 1) == NCH - 1);
    __syncthreads();
    if (last) {
        __threadfence();                // acquire: see all other partials
        float a = 0.f;
#pragma unroll
        for (int c2 = 0; c2 < NCH; ++c2)
            a += partial[((size_t)b * NCH + c2) * 256 + t];
        out[(size_t)b * 256 + t] = a;
    }
}

extern "C" void kernel_launch(void* const* d_in, const int* in_sizes, int n_in,
                              void* d_out, int out_size, void* d_ws, size_t ws_size,
                              hipStream_t stream) {
    const float* q    = (const float*)d_in[0];
    const float* k    = (const float*)d_in[1];
    const float* v    = (const float*)d_in[2];
    const int*   vlen = (const int*)d_in[3];
    const float* wv   = (const float*)d_in[4];
    // d_in[5..7] (w2, w_v2_w, w_v2_b) are dead: softmax over singleton axis == 1.

    float* blend    = (float*)d_ws;                    // B*S floats       (512 KB)
    float* partial  = blend + (size_t)BB * SS;         // B*NCH*256 floats (2 MB)
    int*   counters = (int*)(partial + (size_t)BB * NCH * 256);  // B ints
    float* out      = (float*)d_out;

    k_blend<<<dim3(BB * SS / 32), dim3(256), 0, stream>>>(q, k, wv, blend, counters);
    k_pv   <<<dim3(NCH, BB),      dim3(256), 0, stream>>>(blend, vlen, v, partial, counters, out);
}

// Round 9
// 43.144 us; speedup vs baseline: 6.8731x; 6.8731x over previous
//
#include <hip/hip_runtime.h>

#define BB 64
#define SS 2048
#define DD 128
#define DDV 256
#define NCH 32          // S / 64 chunks for PV
#define RPC 64          // rows per chunk

// tanh(x) = 1 - 2/(e^{2x}+1) with raw v_rcp_f32 (no IEEE refine).
// |rel err| ~1e-7 vs 7.1e-3 output threshold (validated rounds 4-8).
__device__ __forceinline__ float fast_tanh(float x) {
    const float t = __expf(2.0f * x);
    return 1.0f - 2.0f * __builtin_amdgcn_rcpf(t + 1.0f);
}

// ---------------- Kernel 1: blend[b*S+s] = 0.5*scores1 ----------------
// (+0.5 shift dropped: cancels in softmax #1. 0.5 scale folded into w4.)
// 4 waves/block, 8 rows/wave -> 32 rows/block, 4096 blocks. Lanes 0-31 take
// the q half, 32-63 the k half; one float4 per lane per row. At the HBM
// floor (~20 us for 128 MiB).
__global__ __launch_bounds__(256) void k_blend(const float* __restrict__ q,
                                               const float* __restrict__ k,
                                               const float* __restrict__ wv,
                                               float* __restrict__ blend) {
    const int wave = threadIdx.x >> 6;
    const int lane = threadIdx.x & 63;
    const float* src = (lane < 32) ? q : k;
    float4 w4 = *(const float4*)(wv + lane * 4);
    w4.x *= 0.5f; w4.y *= 0.5f; w4.z *= 0.5f; w4.w *= 0.5f;
    const int row0 = blockIdx.x * 32 + wave * 8;
    const float* base = src + (size_t)row0 * DD + (lane & 31) * 4;
#pragma unroll
    for (int i = 0; i < 8; ++i) {
        const float4 x = *(const float4*)(base + (size_t)i * DD);
        float acc = fast_tanh(x.x) * w4.x + fast_tanh(x.y) * w4.y
                  + fast_tanh(x.z) * w4.z + fast_tanh(x.w) * w4.w;
#pragma unroll
        for (int o = 32; o; o >>= 1) acc += __shfl_xor(acc, o, 64);
        if (lane == 0) blend[row0 + i] = acc;
    }
}

// ---------------- Kernel 2: inline stats + PV partials ----------------
// grid (NCH, B), 256 threads. Each working block recomputes its batch's
// double-softmax stats from blend (L2-hot; redundant across the 32 chunks of
// a batch but fully parallel and bitwise identical — NO fences, NO atomics;
// round 8 showed per-block device fences cost ~300 us). Then the proven PV
// pipeline. Blocks fully past valid_len write a zero partial.
__global__ __launch_bounds__(256) void k_pv(const float* __restrict__ blend,
                                            const int* __restrict__ valid,
                                            const float* __restrict__ values,
                                            float* __restrict__ partial) {
    const int c = blockIdx.x, b = blockIdx.y;
    const int t = threadIdx.x;
    const int wid = t >> 6, lane = t & 63;
    const int s0 = c * RPC;
    __shared__ float red[4];
    __shared__ float wsm[RPC];
    __shared__ float4 sacc[256];

    const int L = valid[b];
    float4 acc = {0.f, 0.f, 0.f, 0.f};

    if (s0 < L) {
        // ---- inline stats over the whole batch row ----
        const float* rowp = blend + (size_t)b * SS;
        float v[8];
#pragma unroll
        for (int i = 0; i < 8; ++i) v[i] = rowp[t + i * 256];

        float m = v[0];
#pragma unroll
        for (int i = 1; i < 8; ++i) m = fmaxf(m, v[i]);
#pragma unroll
        for (int o = 32; o; o >>= 1) m = fmaxf(m, __shfl_xor(m, o, 64));
        if (lane == 0) red[wid] = m;
        __syncthreads();
        const float m1 = fmaxf(fmaxf(red[0], red[1]), fmaxf(red[2], red[3]));
        __syncthreads();

        float e[8]; float s = 0.f;
#pragma unroll
        for (int i = 0; i < 8; ++i) { e[i] = expf(v[i] - m1); s += e[i]; }
#pragma unroll
        for (int o = 32; o; o >>= 1) s += __shfl_xor(s, o, 64);
        if (lane == 0) red[wid] = s;
        __syncthreads();
        const float Z1 = red[0] + red[1] + red[2] + red[3];
        __syncthreads();
        const float invZ1 = 1.f / Z1;

        float mm = -1e30f;
#pragma unroll
        for (int i = 0; i < 8; ++i)
            if (t + i * 256 < L) mm = fmaxf(mm, e[i] * invZ1);
#pragma unroll
        for (int o = 32; o; o >>= 1) mm = fmaxf(mm, __shfl_xor(mm, o, 64));
        if (lane == 0) red[wid] = mm;
        __syncthreads();
        const float m2 = fmaxf(fmaxf(red[0], red[1]), fmaxf(red[2], red[3]));
        __syncthreads();

        float s2 = 0.f;
#pragma unroll
        for (int i = 0; i < 8; ++i)
            if (t + i * 256 < L) s2 += expf(e[i] * invZ1 - m2);
#pragma unroll
        for (int o = 32; o; o >>= 1) s2 += __shfl_xor(s2, o, 64);
        if (lane == 0) red[wid] = s2;
        __syncthreads();
        const float Z2 = red[0] + red[1] + red[2] + red[3];
        const float invZ2 = 1.f / Z2;

        // ---- weights for this chunk's 64 rows ----
        if (t < RPC) {
            const int s_ = s0 + t;
            float w = 0.f;
            if (s_ < L)
                w = expf(expf(rowp[s_] - m1) * invZ1 - m2) * invZ2;
            wsm[t] = w;
        }
        __syncthreads();

        // ---- PV ----
        float wr[16];
        bool any = false;
#pragma unroll
        for (int i = 0; i < 16; ++i) { wr[i] = wsm[wid * 16 + i]; any |= (wr[i] != 0.f); }
        if (any) {
            const float* vb = values + ((size_t)b * SS + s0 + wid * 16) * DDV + lane * 4;
#pragma unroll
            for (int i = 0; i < 16; ++i) {
                const float4 v4 = *(const float4*)(vb + (size_t)i * DDV);
                acc.x += wr[i] * v4.x;
                acc.y += wr[i] * v4.y;
                acc.z += wr[i] * v4.z;
                acc.w += wr[i] * v4.w;
            }
        }
    }

    sacc[t] = acc;
    __syncthreads();
    if (t < 64) {
        const float4 a0 = sacc[t], a1 = sacc[t + 64], a2 = sacc[t + 128], a3 = sacc[t + 192];
        float4 r;
        r.x = a0.x + a1.x + a2.x + a3.x;
        r.y = a0.y + a1.y + a2.y + a3.y;
        r.z = a0.z + a1.z + a2.z + a3.z;
        r.w = a0.w + a1.w + a2.w + a3.w;
        *(float4*)(partial + ((size_t)(b * NCH + c)) * 256 + t * 4) = r;
    }
}

// ---------------- Kernel 3: reduce partials -> out ----------------
__global__ __launch_bounds__(256) void k_reduce(const float* __restrict__ partial,
                                                float* __restrict__ out) {
    const int b = blockIdx.x, t = threadIdx.x;
    float acc = 0.f;
#pragma unroll
    for (int c = 0; c < NCH; c++) acc += partial[((size_t)b * NCH + c) * 256 + t];
    out[(size_t)b * 256 + t] = acc;
}

extern "C" void kernel_launch(void* const* d_in, const int* in_sizes, int n_in,
                              void* d_out, int out_size, void* d_ws, size_t ws_size,
                              hipStream_t stream) {
    const float* q    = (const float*)d_in[0];
    const float* k    = (const float*)d_in[1];
    const float* v    = (const float*)d_in[2];
    const int*   vlen = (const int*)d_in[3];
    const float* wv   = (const float*)d_in[4];
    // d_in[5..7] (w2, w_v2_w, w_v2_b) are dead: softmax over singleton axis == 1.

    float* blend   = (float*)d_ws;                 // B*S floats        (512 KB)
    float* partial = blend + (size_t)BB * SS;      // B*NCH*256 floats  (2 MB)
    float* out     = (float*)d_out;

    k_blend <<<dim3(BB * SS / 32), dim3(256), 0, stream>>>(q, k, wv, blend);
    k_pv    <<<dim3(NCH, BB),      dim3(256), 0, stream>>>(blend, vlen, v, partial);
    k_reduce<<<dim3(BB),           dim3(256), 0, stream>>>(partial, out);
}

// Round 10
// 42.961 us; speedup vs baseline: 6.9024x; 1.0043x over previous
//
#include <hip/hip_runtime.h>

#define BB 64
#define SS 2048
#define DD 128
#define DDV 256
#define NCH 32          // S / 64 chunks for PV
#define RPC 64          // rows per chunk

// tanh(x) = 1 - 2/(e^{2x}+1) with raw v_rcp_f32 (no IEEE refine).
// |rel err| ~1e-7 vs 7.1e-3 output threshold (validated rounds 4-9).
__device__ __forceinline__ float fast_tanh(float x) {
    const float t = __expf(2.0f * x);
    return 1.0f - 2.0f * __builtin_amdgcn_rcpf(t + 1.0f);
}

// ---------------- Kernel 1: blend[b*S+s] = 0.5*scores1 ----------------
// (+0.5 shift dropped: cancels in softmax #1.)
// 8 lanes per row: lane covers 32 elements of the 256-wide concat(q,k) row
// (sub 0-3 -> q half, 4-7 -> k half; per i-step each 4-lane group reads a
// contiguous 64 B segment). Weights hoisted to 8 VGPR float4s, reused over
// 16 rows/wave. Reduction: 3 shuffles (within 8 lanes) instead of the old
// 6-deep 64-lane butterfly -> shorter dependence chain, more ILP.
// 4 waves x 16 rows = 64 rows/block, 2048 blocks.
__global__ __launch_bounds__(256) void k_blend(const float* __restrict__ q,
                                               const float* __restrict__ k,
                                               const float* __restrict__ wv,
                                               float* __restrict__ blend) {
    const int wave = threadIdx.x >> 6;
    const int lane = threadIdx.x & 63;
    const int sub  = lane & 7;            // position within the 8-lane row group
    const int rsub = lane >> 3;           // which of the 8 concurrent rows
    const float* src  = (sub < 4) ? q : k;
    const int    eoff = (sub & 3) * 4;    // float offset within the 128-float half

    const float* wbase = wv + ((sub < 4) ? 0 : DD) + eoff;
    float4 w4[8];
#pragma unroll
    for (int i = 0; i < 8; ++i) w4[i] = *(const float4*)(wbase + i * 16);

    const int row_base = blockIdx.x * 64 + wave * 16 + rsub;
#pragma unroll
    for (int j = 0; j < 2; ++j) {
        const int row = row_base + j * 8;
        const float* base = src + (size_t)row * DD + eoff;
        float acc = 0.f;
#pragma unroll
        for (int i = 0; i < 8; ++i) {
            const float4 x = *(const float4*)(base + i * 16);
            acc += fast_tanh(x.x) * w4[i].x + fast_tanh(x.y) * w4[i].y
                 + fast_tanh(x.z) * w4[i].z + fast_tanh(x.w) * w4[i].w;
        }
        acc += __shfl_xor(acc, 1, 64);
        acc += __shfl_xor(acc, 2, 64);
        acc += __shfl_xor(acc, 4, 64);
        if (sub == 0) blend[row] = 0.5f * acc;
    }
}

// ---------------- Kernel 2: inline stats + PV partials ----------------
// grid (NCH, B), 256 threads. Each working block recomputes its batch's
// double-softmax stats from blend (L2-hot; redundant across the 32 chunks of
// a batch but fully parallel and bitwise identical — NO fences, NO atomics;
// round 8 showed per-block device fences cost ~300 us). Stats loads are
// 2x float4 per thread (elements t*8 .. t*8+7). Then the proven PV pipeline.
// Blocks fully past valid_len write a zero partial.
__global__ __launch_bounds__(256) void k_pv(const float* __restrict__ blend,
                                            const int* __restrict__ valid,
                                            const float* __restrict__ values,
                                            float* __restrict__ partial) {
    const int c = blockIdx.x, b = blockIdx.y;
    const int t = threadIdx.x;
    const int wid = t >> 6, lane = t & 63;
    const int s0 = c * RPC;
    __shared__ float red[4];
    __shared__ float wsm[RPC];
    __shared__ float4 sacc[256];

    const int L = valid[b];
    float4 acc = {0.f, 0.f, 0.f, 0.f};

    if (s0 < L) {
        // ---- inline stats over the whole batch row ----
        const float* rowp = blend + (size_t)b * SS;
        float v[8];
        {
            const float4 va = *(const float4*)(rowp + t * 8);
            const float4 vb = *(const float4*)(rowp + t * 8 + 4);
            v[0] = va.x; v[1] = va.y; v[2] = va.z; v[3] = va.w;
            v[4] = vb.x; v[5] = vb.y; v[6] = vb.z; v[7] = vb.w;
        }

        float m = v[0];
#pragma unroll
        for (int i = 1; i < 8; ++i) m = fmaxf(m, v[i]);
#pragma unroll
        for (int o = 32; o; o >>= 1) m = fmaxf(m, __shfl_xor(m, o, 64));
        if (lane == 0) red[wid] = m;
        __syncthreads();
        const float m1 = fmaxf(fmaxf(red[0], red[1]), fmaxf(red[2], red[3]));
        __syncthreads();

        float e[8]; float s = 0.f;
#pragma unroll
        for (int i = 0; i < 8; ++i) { e[i] = expf(v[i] - m1); s += e[i]; }
#pragma unroll
        for (int o = 32; o; o >>= 1) s += __shfl_xor(s, o, 64);
        if (lane == 0) red[wid] = s;
        __syncthreads();
        const float Z1 = red[0] + red[1] + red[2] + red[3];
        __syncthreads();
        const float invZ1 = 1.f / Z1;

        float mm = -1e30f;
#pragma unroll
        for (int i = 0; i < 8; ++i)
            if (t * 8 + i < L) mm = fmaxf(mm, e[i] * invZ1);
#pragma unroll
        for (int o = 32; o; o >>= 1) mm = fmaxf(mm, __shfl_xor(mm, o, 64));
        if (lane == 0) red[wid] = mm;
        __syncthreads();
        const float m2 = fmaxf(fmaxf(red[0], red[1]), fmaxf(red[2], red[3]));
        __syncthreads();

        float s2 = 0.f;
#pragma unroll
        for (int i = 0; i < 8; ++i)
            if (t * 8 + i < L) s2 += expf(e[i] * invZ1 - m2);
#pragma unroll
        for (int o = 32; o; o >>= 1) s2 += __shfl_xor(s2, o, 64);
        if (lane == 0) red[wid] = s2;
        __syncthreads();
        const float Z2 = red[0] + red[1] + red[2] + red[3];
        const float invZ2 = 1.f / Z2;

        // ---- weights for this chunk's 64 rows ----
        if (t < RPC) {
            const int s_ = s0 + t;
            float w = 0.f;
            if (s_ < L)
                w = expf(expf(rowp[s_] - m1) * invZ1 - m2) * invZ2;
            wsm[t] = w;
        }
        __syncthreads();

        // ---- PV ----
        float wr[16];
        bool any = false;
#pragma unroll
        for (int i = 0; i < 16; ++i) { wr[i] = wsm[wid * 16 + i]; any |= (wr[i] != 0.f); }
        if (any) {
            const float* vb = values + ((size_t)b * SS + s0 + wid * 16) * DDV + lane * 4;
#pragma unroll
            for (int i = 0; i < 16; ++i) {
                const float4 v4 = *(const float4*)(vb + (size_t)i * DDV);
                acc.x += wr[i] * v4.x;
                acc.y += wr[i] * v4.y;
                acc.z += wr[i] * v4.z;
                acc.w += wr[i] * v4.w;
            }
        }
    }

    sacc[t] = acc;
    __syncthreads();
    if (t < 64) {
        const float4 a0 = sacc[t], a1 = sacc[t + 64], a2 = sacc[t + 128], a3 = sacc[t + 192];
        float4 r;
        r.x = a0.x + a1.x + a2.x + a3.x;
        r.y = a0.y + a1.y + a2.y + a3.y;
        r.z = a0.z + a1.z + a2.z + a3.z;
        r.w = a0.w + a1.w + a2.w + a3.w;
        *(float4*)(partial + ((size_t)(b * NCH + c)) * 256 + t * 4) = r;
    }
}

// ---------------- Kernel 3: reduce partials -> out ----------------
__global__ __launch_bounds__(256) void k_reduce(const float* __restrict__ partial,
                                                float* __restrict__ out) {
    const int b = blockIdx.x, t = threadIdx.x;
    float acc = 0.f;
#pragma unroll
    for (int c = 0; c < NCH; c++) acc += partial[((size_t)b * NCH + c) * 256 + t];
    out[(size_t)b * 256 + t] = acc;
}

extern "C" void kernel_launch(void* const* d_in, const int* in_sizes, int n_in,
                              void* d_out, int out_size, void* d_ws, size_t ws_size,
                              hipStream_t stream) {
    const float* q    = (const float*)d_in[0];
    const float* k    = (const float*)d_in[1];
    const float* v    = (const float*)d_in[2];
    const int*   vlen = (const int*)d_in[3];
    const float* wv   = (const float*)d_in[4];
    // d_in[5..7] (w2, w_v2_w, w_v2_b) are dead: softmax over singleton axis == 1.

    float* blend   = (float*)d_ws;                 // B*S floats        (512 KB)
    float* partial = blend + (size_t)BB * SS;      // B*NCH*256 floats  (2 MB)
    float* out     = (float*)d_out;

    k_blend <<<dim3(BB * SS / 64), dim3(256), 0, stream>>>(q, k, wv, blend);
    k_pv    <<<dim3(NCH, BB),      dim3(256), 0, stream>>>(blend, vlen, v, partial);
    k_reduce<<<dim3(BB),           dim3(256), 0, stream>>>(partial, out);
}